// Round 2
// baseline (1593.899 us; speedup 1.0000x reference)
//
#include <hip/hip_runtime.h>
#include <math.h>

// ---------------------------------------------------------------------------
// MuellerMatrixPyramid, fp32, MI355X.
//   conv0 (48->48, 512^2) -> y0
//   mm0   (y0 -> m0, 17ch)
//   oconv0(m0 -> out[:,0:17])
//   pool  (y0 -> x1, 128^2)
//   conv1 (48->48, 128^2) -> y1
//   mm1   (y1 -> m1)
//   up    (m1 -> u, bicubic a=-0.75 align_corners, 128->512)
//   oconv1(u -> out[:,17:34])
// Conv: channel-tiled rounds (CTILE=4) — 2 barriers per 4 channels instead of
// per channel; staging offsets precomputed once. FMA order per output pixel is
// identical to the fp32 reference ordering used in round 1 (absmax-sensitive).
// ---------------------------------------------------------------------------

__device__ __forceinline__ float leakyf(float t) { return t >= 0.0f ? t : 0.01f * t; }

// ---------------- 3x3 conv + bias + leaky, channel-tiled -------------------
// 256 threads = XG x-groups * TH rows; each thread PX px * OCPT out-channels.
// grid.z = B * NG.
template<int CIN, int OCPT, int CTILE, int PX, int TW, int MINW>
__global__ __launch_bounds__(256, MINW)
void conv3x3_leaky(const float* __restrict__ in, const float* __restrict__ wgt,
                   const float* __restrict__ bias, float* __restrict__ out,
                   int H, int W, int COUT, int NG,
                   int in_bstride, int out_bstride, int out_coff)
{
    constexpr int XG     = TW / PX;           // x-groups
    constexpr int TH     = 256 / XG;          // tile height
    constexpr int COLS   = TW + 2;
    constexpr int ROWS   = TH + 2;
    constexpr int STRIDE = (COLS + 3) & ~3;   // 16B-aligned rows
    constexpr int TSZ    = ROWS * STRIDE;
    constexpr int ELEMS  = ROWS * COLS;
    constexpr int K      = (ELEMS + 255) / 256;
    constexpr int NV     = PX + 2;

    __shared__ float tile[CTILE * TSZ];
    __shared__ float wlds[CTILE * OCPT * 12];
    __shared__ float blds[OCPT];

    const int tid   = threadIdx.x;
    const int tx    = tid & (XG - 1);
    const int ty    = tid / XG;
    const int g     = blockIdx.z % NG;
    const int b     = blockIdx.z / NG;
    const int obase = g * OCPT;
    const int row0  = blockIdx.y * TH;
    const int col0  = blockIdx.x * TW;
    const int HW    = H * W;

    if (tid < OCPT) {
        int og = obase + tid;
        blds[tid] = (og < COUT) ? bias[og] : 0.0f;
    }

    // precompute staging offsets once (goff = -1 -> zero-fill; loff = -1 -> no slot)
    int goff[K], loff[K];
#pragma unroll
    for (int k = 0; k < K; ++k) {
        int idx = tid + k * 256;
        if (idx < ELEMS) {
            int r  = idx / COLS;
            int cc = idx - r * COLS;
            int gr = row0 - 1 + r;
            int gc = col0 - 1 + cc;
            bool v = (gr >= 0 && gr < H && gc >= 0 && gc < W);
            goff[k] = v ? (gr * W + gc) : -1;
            loff[k] = r * STRIDE + cc;
        } else {
            goff[k] = -1;
            loff[k] = -1;
        }
    }

    float acc[OCPT][PX];
#pragma unroll
    for (int o = 0; o < OCPT; ++o)
#pragma unroll
        for (int p = 0; p < PX; ++p) acc[o][p] = 0.0f;

    const float* inb = in + b * in_bstride;

    for (int c0 = 0; c0 < CIN; c0 += CTILE) {
        __syncthreads();   // previous round's LDS reads done

        // stage this round's weights: wlds[ct][o][k], k padded to 12
        for (int idx = tid; idx < CTILE * OCPT * 9; idx += 256) {
            int ct = idx / (OCPT * 9);
            int r2 = idx - ct * (OCPT * 9);
            int o  = r2 / 9;
            int k2 = r2 - o * 9;
            int c  = c0 + ct;
            int og = obase + o;
            wlds[(ct * OCPT + o) * 12 + k2] =
                (c < CIN && og < COUT) ? wgt[(og * CIN + c) * 9 + k2] : 0.0f;
        }

        // stage CTILE input tiles (all loads independent -> one latency exposure)
#pragma unroll
        for (int ct = 0; ct < CTILE; ++ct) {
            int c = c0 + ct;
            if (c < CIN) {
                const float* ic = inb + c * HW;
                float* tb = &tile[ct * TSZ];
#pragma unroll
                for (int k = 0; k < K; ++k) {
                    if (loff[k] >= 0) {
                        float v = 0.0f;
                        int go = goff[k];
                        if (go >= 0) v = ic[go];
                        tb[loff[k]] = v;
                    }
                }
            }
        }
        __syncthreads();

        // compute: channels in ascending order (bit-identical accumulation order)
#pragma unroll
        for (int ct = 0; ct < CTILE; ++ct) {
            if (c0 + ct < CIN) {
                float v[3][NV];
#pragma unroll
                for (int rr = 0; rr < 3; ++rr) {
                    const float* tp = &tile[ct * TSZ + (ty + rr) * STRIDE + tx * PX];
                    float4 a0 = *(const float4*)tp;
                    v[rr][0] = a0.x; v[rr][1] = a0.y; v[rr][2] = a0.z; v[rr][3] = a0.w;
                    if constexpr (PX == 8) {
                        float4 a1 = *(const float4*)(tp + 4);
                        float2 a2 = *(const float2*)(tp + 8);
                        v[rr][4] = a1.x; v[rr][5] = a1.y; v[rr][6] = a1.z; v[rr][7] = a1.w;
                        v[rr][8] = a2.x; v[rr][9] = a2.y;
                    } else {
                        float2 a1 = *(const float2*)(tp + 4);
                        v[rr][4] = a1.x; v[rr][5] = a1.y;
                    }
                }
#pragma unroll
                for (int o = 0; o < OCPT; ++o) {
                    const float* wp = &wlds[(ct * OCPT + o) * 12];
                    float4 w0 = *(const float4*)wp;
                    float4 w1 = *(const float4*)(wp + 4);
                    float w8 = wp[8];
                    float wk[9] = {w0.x, w0.y, w0.z, w0.w, w1.x, w1.y, w1.z, w1.w, w8};
#pragma unroll
                    for (int px = 0; px < PX; ++px) {
                        float s = acc[o][px];
#pragma unroll
                        for (int kr = 0; kr < 3; ++kr)
#pragma unroll
                            for (int kc = 0; kc < 3; ++kc)
                                s = fmaf(wk[kr * 3 + kc], v[kr][px + kc], s);
                        acc[o][px] = s;
                    }
                }
            }
        }
    }

    const int orow = row0 + ty;
    float* outb = out + b * out_bstride;
#pragma unroll
    for (int o = 0; o < OCPT; ++o) {
        int og = obase + o;
        if (og < COUT) {
            float bv = blds[o];
            float r[PX];
#pragma unroll
            for (int p = 0; p < PX; ++p) { float t = acc[o][p] + bv; r[p] = leakyf(t); }
            float* op = outb + ((out_coff + og) * H + orow) * W + col0 + tx * PX;
#pragma unroll
            for (int q = 0; q < PX / 4; ++q)
                *(float4*)(op + 4 * q) = make_float4(r[4*q], r[4*q+1], r[4*q+2], r[4*q+3]);
        }
    }
}

// ---------------- 4x4 inverse (double, adjugate) ---------------------------
__device__ __forceinline__ void inv4x4(const double* m, double* invOut)
{
    double inv[16];
    inv[0]  =  m[5]*m[10]*m[15] - m[5]*m[11]*m[14] - m[9]*m[6]*m[15] + m[9]*m[7]*m[14] + m[13]*m[6]*m[11] - m[13]*m[7]*m[10];
    inv[4]  = -m[4]*m[10]*m[15] + m[4]*m[11]*m[14] + m[8]*m[6]*m[15] - m[8]*m[7]*m[14] - m[12]*m[6]*m[11] + m[12]*m[7]*m[10];
    inv[8]  =  m[4]*m[9]*m[15]  - m[4]*m[11]*m[13] - m[8]*m[5]*m[15] + m[8]*m[7]*m[13] + m[12]*m[5]*m[11] - m[12]*m[7]*m[9];
    inv[12] = -m[4]*m[9]*m[14]  + m[4]*m[10]*m[13] + m[8]*m[5]*m[14] - m[8]*m[6]*m[13] - m[12]*m[5]*m[10] + m[12]*m[6]*m[9];
    inv[1]  = -m[1]*m[10]*m[15] + m[1]*m[11]*m[14] + m[9]*m[2]*m[15] - m[9]*m[3]*m[14] - m[13]*m[2]*m[11] + m[13]*m[3]*m[10];
    inv[5]  =  m[0]*m[10]*m[15] - m[0]*m[11]*m[14] - m[8]*m[2]*m[15] + m[8]*m[3]*m[14] + m[12]*m[2]*m[11] - m[12]*m[3]*m[10];
    inv[9]  = -m[0]*m[9]*m[15]  + m[0]*m[11]*m[13] + m[8]*m[1]*m[15] - m[8]*m[3]*m[13] - m[12]*m[1]*m[11] + m[12]*m[3]*m[9];
    inv[13] =  m[0]*m[9]*m[14]  - m[0]*m[10]*m[13] - m[8]*m[1]*m[14] + m[8]*m[2]*m[13] + m[12]*m[1]*m[10] - m[12]*m[2]*m[9];
    inv[2]  =  m[1]*m[6]*m[15]  - m[1]*m[7]*m[14]  - m[5]*m[2]*m[15] + m[5]*m[3]*m[14] + m[13]*m[2]*m[7]  - m[13]*m[3]*m[6];
    inv[6]  = -m[0]*m[6]*m[15]  + m[0]*m[7]*m[14]  + m[4]*m[2]*m[15] - m[4]*m[3]*m[14] - m[12]*m[2]*m[7]  + m[12]*m[3]*m[6];
    inv[10] =  m[0]*m[5]*m[15]  - m[0]*m[7]*m[13]  - m[4]*m[1]*m[15] + m[4]*m[3]*m[13] + m[12]*m[1]*m[7]  - m[12]*m[3]*m[5];
    inv[14] = -m[0]*m[5]*m[14]  + m[0]*m[6]*m[13]  + m[4]*m[1]*m[14] - m[4]*m[2]*m[13] - m[12]*m[1]*m[6]  + m[12]*m[2]*m[5];
    inv[3]  = -m[1]*m[6]*m[11]  + m[1]*m[7]*m[10]  + m[5]*m[2]*m[11] - m[5]*m[3]*m[10] - m[9]*m[2]*m[7]   + m[9]*m[3]*m[6];
    inv[7]  =  m[0]*m[6]*m[11]  - m[0]*m[7]*m[10]  - m[4]*m[2]*m[11] + m[4]*m[3]*m[10] + m[8]*m[2]*m[7]   - m[8]*m[3]*m[6];
    inv[11] = -m[0]*m[5]*m[11]  + m[0]*m[7]*m[9]   + m[4]*m[1]*m[11] - m[4]*m[3]*m[9]  - m[8]*m[1]*m[7]   + m[8]*m[3]*m[5];
    inv[15] =  m[0]*m[5]*m[10]  - m[0]*m[6]*m[9]   - m[4]*m[1]*m[10] + m[4]*m[2]*m[9]  + m[8]*m[1]*m[6]   - m[8]*m[2]*m[5];
    double det = m[0]*inv[0] + m[1]*inv[4] + m[2]*inv[8] + m[3]*inv[12];
    det = 1.0 / det;
#pragma unroll
    for (int i = 0; i < 16; ++i) invOut[i] = inv[i] * det;
}

__device__ __forceinline__ void matmul4(const double* A, const double* B, double* C)
{
#pragma unroll
    for (int r = 0; r < 4; ++r)
#pragma unroll
        for (int c = 0; c < 4; ++c) {
            double s = 0.0;
#pragma unroll
            for (int k = 0; k < 4; ++k) s += A[r * 4 + k] * B[k * 4 + c];
            C[r * 4 + c] = s;
        }
}

// ---------------- mm_features: (b,48,h,w) -> (b,17,h,w) --------------------
// Liveness-minimized: iA computed before F is loaded, iW after T=iA*F, so the
// peak double count stays ~50 (no scratch spills).
__global__ __launch_bounds__(256)
void mm_features_kernel(const float* __restrict__ y, float* __restrict__ m, int HW, int n)
{
    int p = blockIdx.x * 256 + threadIdx.x;
    if (p >= n) return;
    int b  = p / HW;
    int sp = p - b * HW;
    const float* base = y + (size_t)b * 48 * HW + sp;

    double A[16];
#pragma unroll
    for (int i = 0; i < 16; ++i) {
        double e = (i == 0 || i == 5 || i == 10 || i == 15) ? 1e-4 : 0.0;
        A[i] = (double)base[(16 + i) * HW] + e;
    }
    double iA[16];
    inv4x4(A, iA);                     // A dead

    double F[16];
    double s = 0.0;
#pragma unroll
    for (int i = 0; i < 16; ++i) { F[i] = (double)base[i * HW]; }
#pragma unroll
    for (int i = 0; i < 16; ++i) s += F[i];
    s *= (1.0 / 16.0);

    double T[16];
    matmul4(iA, F, T);                 // iA, F dead

    double Wm[16];
#pragma unroll
    for (int i = 0; i < 16; ++i) {
        double e = (i == 0 || i == 5 || i == 10 || i == 15) ? 1e-4 : 0.0;
        Wm[i] = (double)base[(32 + i) * HW] + e;
    }
    double iW[16];
    inv4x4(Wm, iW);                    // Wm dead

    double M[16];
    matmul4(T, iW, M);

    float* ob = m + (size_t)b * 17 * HW + sp;
    ob[0] = (float)s;
#pragma unroll
    for (int i = 0; i < 16; ++i) ob[(1 + i) * HW] = (float)M[i];
}

// ---------------- 4x4 maxpool: (2,48,512,512) -> (2,48,128,128) ------------
__global__ __launch_bounds__(256)
void maxpool4_kernel(const float* __restrict__ in, float* __restrict__ out, int n)
{
    int idx = blockIdx.x * 256 + threadIdx.x;
    if (idx >= n) return;
    int ow = idx & 127;
    int oh = (idx >> 7) & 127;
    int ct = idx >> 14;                 // b*48 + c
    const float* p = in + ct * 262144 + (oh * 4) * 512 + ow * 4;
    float mx = -3.4e38f;
#pragma unroll
    for (int r = 0; r < 4; ++r) {
        float4 v = *(const float4*)(p + r * 512);
        mx = fmaxf(mx, fmaxf(fmaxf(v.x, v.y), fmaxf(v.z, v.w)));
    }
    out[idx] = mx;
}

// ---------------- bicubic x4 upsample 128->512, align_corners, a=-0.75 -----
__device__ __forceinline__ double cubw(double t)
{
    const double a = -0.75;
    t = fabs(t);
    if (t <= 1.0) return ((a + 2.0) * t - (a + 3.0)) * t * t + 1.0;
    if (t < 2.0)  return (((t - 5.0) * t + 8.0) * t - 4.0) * a;
    return 0.0;
}

__global__ __launch_bounds__(256)
void bicubic_up4_kernel(const float* __restrict__ src, float* __restrict__ dst, int n)
{
    int idx = blockIdx.x * 256 + threadIdx.x;
    if (idx >= n) return;
    int P  = idx & 511;
    int O  = (idx >> 9) & 511;
    int bc = idx >> 18;                 // b*17 + c
    const double scale = 127.0 / 511.0;
    double sh = O * scale, sw = P * scale;
    int i0 = (int)floor(sh), j0 = (int)floor(sw);
    double wh[4], ww[4];
#pragma unroll
    for (int k = 0; k < 4; ++k) {
        wh[k] = cubw(sh - (double)(i0 + k - 1));
        ww[k] = cubw(sw - (double)(j0 + k - 1));
    }
    const float* sp = src + bc * 16384;
    double acc = 0.0;
#pragma unroll
    for (int ki = 0; ki < 4; ++ki) {
        int ih = min(max(i0 - 1 + ki, 0), 127);
        double rs = 0.0;
#pragma unroll
        for (int kj = 0; kj < 4; ++kj) {
            int iw = min(max(j0 - 1 + kj, 0), 127);
            rs += ww[kj] * (double)sp[ih * 128 + iw];
        }
        acc += wh[ki] * rs;
    }
    dst[idx] = (float)acc;
}

// ---------------------------------------------------------------------------
extern "C" void kernel_launch(void* const* d_in, const int* in_sizes, int n_in,
                              void* d_out, int out_size, void* d_ws, size_t ws_size,
                              hipStream_t stream)
{
    const float* x   = (const float*)d_in[0];
    const float* iW0 = (const float*)d_in[1];
    const float* iB0 = (const float*)d_in[2];
    const float* iW1 = (const float*)d_in[3];
    const float* iB1 = (const float*)d_in[4];
    const float* oW0 = (const float*)d_in[5];
    const float* oB0 = (const float*)d_in[6];
    const float* oW1 = (const float*)d_in[7];
    const float* oB1 = (const float*)d_in[8];
    float* out = (float*)d_out;
    float* ws  = (float*)d_ws;

    // workspace layout (floats)
    float* y0 = ws;                     //  2*48*512*512 = 25165824
    float* m0 = ws + 25165824;          //  2*17*512*512 =  8912896
    float* x1 = ws + 34078720;          //  2*48*128*128 =  1572864
    float* y1 = ws + 35651584;          //  1572864
    float* m1 = ws + 37224448;          //  2*17*128*128 =   557056
    float* u  = ws;                     //  reuse y0 region (y0 dead by then)

    // level 0
    conv3x3_leaky<48, 8, 4, 8, 64, 3><<<dim3(8, 16, 12), 256, 0, stream>>>(
        x, iW0, iB0, y0, 512, 512, 48, 6, 48 * 512 * 512, 48 * 512 * 512, 0);
    mm_features_kernel<<<(2 * 512 * 512) / 256, 256, 0, stream>>>(y0, m0, 512 * 512, 2 * 512 * 512);
    conv3x3_leaky<17, 9, 4, 8, 64, 3><<<dim3(8, 16, 4), 256, 0, stream>>>(
        m0, oW0, oB0, out, 512, 512, 17, 2, 17 * 512 * 512, 34 * 512 * 512, 0);
    maxpool4_kernel<<<(2 * 48 * 128 * 128) / 256, 256, 0, stream>>>(y0, x1, 2 * 48 * 128 * 128);

    // level 1 (128^2: 32x32 tiles, OCPT=4 -> 384 blocks for CU coverage)
    conv3x3_leaky<48, 4, 4, 4, 32, 4><<<dim3(4, 4, 24), 256, 0, stream>>>(
        x1, iW1, iB1, y1, 128, 128, 48, 12, 48 * 128 * 128, 48 * 128 * 128, 0);
    mm_features_kernel<<<(2 * 128 * 128) / 256, 256, 0, stream>>>(y1, m1, 128 * 128, 2 * 128 * 128);
    bicubic_up4_kernel<<<(2 * 17 * 512 * 512) / 256, 256, 0, stream>>>(m1, u, 2 * 17 * 512 * 512);
    conv3x3_leaky<17, 9, 4, 8, 64, 3><<<dim3(8, 16, 4), 256, 0, stream>>>(
        u, oW1, oB1, out, 512, 512, 17, 2, 17 * 512 * 512, 34 * 512 * 512, 17);
}

// Round 3
// 694.914 us; speedup vs baseline: 2.2937x; 2.2937x over previous
//
#include <hip/hip_runtime.h>
#include <math.h>

// ---------------------------------------------------------------------------
// MuellerMatrixPyramid, fp32, MI355X.
//   conv0 (48->48, 512^2) -> y0
//   mm0   (y0 -> m0, 17ch)
//   oconv0(m0 -> out[:,0:17])
//   pool  (y0 -> x1, 128^2)
//   conv1 (48->48, 128^2) -> y1
//   mm1   (y1 -> m1)
//   up    (m1 -> u, bicubic a=-0.75 align_corners, 128->512)
//   oconv1(u -> out[:,17:34])
//
// Conv: software-pipelined, double-buffered LDS, ONE barrier per channel:
//   load(c+1) into regs -> compute(c) from LDS -> ds_write(c+1) -> barrier.
// Load latency hides behind ~1150 cycles of FMA issue per channel.
// MINW=2 (VGPR cap 256): round-2 spill catastrophe was launch_bounds(256,3)
// capping at ~170 while CTILE=4 demanded ~200+ regs.
// FMA order per output pixel (c asc, kr, kc) identical to rounds 1/2.
// ---------------------------------------------------------------------------

__device__ __forceinline__ float leakyf(float t) { return t >= 0.0f ? t : 0.01f * t; }

// 256 threads = XG x-groups * TH rows; each thread PX px * OCPT out-channels.
// grid.z = B * NG.
template<int CIN, int OCPT, int PX, int TW>
__global__ __launch_bounds__(256, 2)
void conv3x3_leaky(const float* __restrict__ in, const float* __restrict__ wgt,
                   const float* __restrict__ bias, float* __restrict__ out,
                   int H, int W, int COUT, int NG,
                   int in_bstride, int out_bstride, int out_coff)
{
    constexpr int XG     = TW / PX;
    constexpr int TH     = 256 / XG;
    constexpr int COLS   = TW + 2;
    constexpr int ROWS   = TH + 2;
    constexpr int STRIDE = (COLS + 3) & ~3;   // 16B-aligned rows
    constexpr int TSZ    = ROWS * STRIDE;
    constexpr int ELEMS  = ROWS * COLS;
    constexpr int K      = (ELEMS + 255) / 256;
    constexpr int NV     = PX + 2;

    __shared__ float tile[2 * TSZ];           // double buffer
    __shared__ float wlds[CIN * OCPT * 12];   // all weights, staged once
    __shared__ float blds[OCPT];

    const int tid   = threadIdx.x;
    const int tx    = tid & (XG - 1);
    const int ty    = tid / XG;
    const int g     = blockIdx.z % NG;
    const int b     = blockIdx.z / NG;
    const int obase = g * OCPT;
    const int row0  = blockIdx.y * TH;
    const int col0  = blockIdx.x * TW;
    const int HW    = H * W;

    // stage ALL weights once: wlds[c][o][k], k padded to 12
    for (int idx = tid; idx < CIN * OCPT * 9; idx += 256) {
        int c  = idx / (OCPT * 9);
        int r2 = idx - c * (OCPT * 9);
        int o  = r2 / 9;
        int k2 = r2 - o * 9;
        int og = obase + o;
        wlds[(c * OCPT + o) * 12 + k2] = (og < COUT) ? wgt[(og * CIN + c) * 9 + k2] : 0.0f;
    }
    if (tid < OCPT) {
        int og = obase + tid;
        blds[tid] = (og < COUT) ? bias[og] : 0.0f;
    }

    // loop-invariant staging offsets (K regs each)
    int goff[K], loff[K];
#pragma unroll
    for (int k = 0; k < K; ++k) {
        int idx = tid + k * 256;
        if (idx < ELEMS) {
            int r  = idx / COLS;
            int cc = idx - r * COLS;
            int gr = row0 - 1 + r;
            int gc = col0 - 1 + cc;
            bool v = (gr >= 0 && gr < H && gc >= 0 && gc < W);
            goff[k] = v ? (gr * W + gc) : -1;
            loff[k] = r * STRIDE + cc;
        } else {
            goff[k] = -1;
            loff[k] = -1;
        }
    }

    const float* inb = in + b * in_bstride;

    // prologue: stage channel 0 into buffer 0
    float sreg[K];
    {
        const float* ic = inb;   // c = 0
#pragma unroll
        for (int k = 0; k < K; ++k) {
            float v = 0.0f;
            if (goff[k] >= 0) v = ic[goff[k]];
            sreg[k] = v;
        }
#pragma unroll
        for (int k = 0; k < K; ++k)
            if (loff[k] >= 0) tile[loff[k]] = sreg[k];
    }
    __syncthreads();

    float acc[OCPT][PX];
#pragma unroll
    for (int o = 0; o < OCPT; ++o)
#pragma unroll
        for (int p = 0; p < PX; ++p) acc[o][p] = 0.0f;

    for (int c = 0; c < CIN; ++c) {
        // issue next channel's loads (latency overlaps this channel's FMAs)
        if (c + 1 < CIN) {
            const float* ic = inb + (c + 1) * HW;
#pragma unroll
            for (int k = 0; k < K; ++k) {
                float v = 0.0f;
                if (goff[k] >= 0) v = ic[goff[k]];
                sreg[k] = v;
            }
        }

        // compute channel c from buffer (c&1)
        {
            const float* tb = &tile[(c & 1) * TSZ];
            float v[3][NV];
#pragma unroll
            for (int rr = 0; rr < 3; ++rr) {
                const float* tp = tb + (ty + rr) * STRIDE + tx * PX;
                float4 a0 = *(const float4*)tp;
                v[rr][0] = a0.x; v[rr][1] = a0.y; v[rr][2] = a0.z; v[rr][3] = a0.w;
                if constexpr (PX == 8) {
                    float4 a1 = *(const float4*)(tp + 4);
                    float2 a2 = *(const float2*)(tp + 8);
                    v[rr][4] = a1.x; v[rr][5] = a1.y; v[rr][6] = a1.z; v[rr][7] = a1.w;
                    v[rr][8] = a2.x; v[rr][9] = a2.y;
                } else {
                    float2 a1 = *(const float2*)(tp + 4);
                    v[rr][4] = a1.x; v[rr][5] = a1.y;
                }
            }
#pragma unroll
            for (int o = 0; o < OCPT; ++o) {
                const float* wp = &wlds[(c * OCPT + o) * 12];
                float4 w0 = *(const float4*)wp;
                float4 w1 = *(const float4*)(wp + 4);
                float w8 = wp[8];
                float wk[9] = {w0.x, w0.y, w0.z, w0.w, w1.x, w1.y, w1.z, w1.w, w8};
#pragma unroll
                for (int px = 0; px < PX; ++px) {
                    float s = acc[o][px];
#pragma unroll
                    for (int kr = 0; kr < 3; ++kr)
#pragma unroll
                        for (int kc = 0; kc < 3; ++kc)
                            s = fmaf(wk[kr * 3 + kc], v[kr][px + kc], s);
                    acc[o][px] = s;
                }
            }
        }

        // write next channel's tile into the other buffer, then barrier
        if (c + 1 < CIN) {
            float* tb = &tile[((c + 1) & 1) * TSZ];
#pragma unroll
            for (int k = 0; k < K; ++k)
                if (loff[k] >= 0) tb[loff[k]] = sreg[k];
            __syncthreads();   // uniform branch (c uniform) -> legal
        }
    }

    const int orow = row0 + ty;
    float* outb = out + b * out_bstride;
#pragma unroll
    for (int o = 0; o < OCPT; ++o) {
        int og = obase + o;
        if (og < COUT) {
            float bv = blds[o];
            float r[PX];
#pragma unroll
            for (int p = 0; p < PX; ++p) { float t = acc[o][p] + bv; r[p] = leakyf(t); }
            float* op = outb + ((out_coff + og) * H + orow) * W + col0 + tx * PX;
#pragma unroll
            for (int q = 0; q < PX / 4; ++q)
                *(float4*)(op + 4 * q) = make_float4(r[4*q], r[4*q+1], r[4*q+2], r[4*q+3]);
        }
    }
}

// ---------------- 4x4 inverse (double, adjugate) ---------------------------
__device__ __forceinline__ void inv4x4(const double* m, double* invOut)
{
    double inv[16];
    inv[0]  =  m[5]*m[10]*m[15] - m[5]*m[11]*m[14] - m[9]*m[6]*m[15] + m[9]*m[7]*m[14] + m[13]*m[6]*m[11] - m[13]*m[7]*m[10];
    inv[4]  = -m[4]*m[10]*m[15] + m[4]*m[11]*m[14] + m[8]*m[6]*m[15] - m[8]*m[7]*m[14] - m[12]*m[6]*m[11] + m[12]*m[7]*m[10];
    inv[8]  =  m[4]*m[9]*m[15]  - m[4]*m[11]*m[13] - m[8]*m[5]*m[15] + m[8]*m[7]*m[13] + m[12]*m[5]*m[11] - m[12]*m[7]*m[9];
    inv[12] = -m[4]*m[9]*m[14]  + m[4]*m[10]*m[13] + m[8]*m[5]*m[14] - m[8]*m[6]*m[13] - m[12]*m[5]*m[10] + m[12]*m[6]*m[9];
    inv[1]  = -m[1]*m[10]*m[15] + m[1]*m[11]*m[14] + m[9]*m[2]*m[15] - m[9]*m[3]*m[14] - m[13]*m[2]*m[11] + m[13]*m[3]*m[10];
    inv[5]  =  m[0]*m[10]*m[15] - m[0]*m[11]*m[14] - m[8]*m[2]*m[15] + m[8]*m[3]*m[14] + m[12]*m[2]*m[11] - m[12]*m[3]*m[10];
    inv[9]  = -m[0]*m[9]*m[15]  + m[0]*m[11]*m[13] + m[8]*m[1]*m[15] - m[8]*m[3]*m[13] - m[12]*m[1]*m[11] + m[12]*m[3]*m[9];
    inv[13] =  m[0]*m[9]*m[14]  - m[0]*m[10]*m[13] - m[8]*m[1]*m[14] + m[8]*m[2]*m[13] + m[12]*m[1]*m[10] - m[12]*m[2]*m[9];
    inv[2]  =  m[1]*m[6]*m[15]  - m[1]*m[7]*m[14]  - m[5]*m[2]*m[15] + m[5]*m[3]*m[14] + m[13]*m[2]*m[7]  - m[13]*m[3]*m[6];
    inv[6]  = -m[0]*m[6]*m[15]  + m[0]*m[7]*m[14]  + m[4]*m[2]*m[15] - m[4]*m[3]*m[14] - m[12]*m[2]*m[7]  + m[12]*m[3]*m[6];
    inv[10] =  m[0]*m[5]*m[15]  - m[0]*m[7]*m[13]  - m[4]*m[1]*m[15] + m[4]*m[3]*m[13] + m[12]*m[1]*m[7]  - m[12]*m[3]*m[5];
    inv[14] = -m[0]*m[5]*m[14]  + m[0]*m[6]*m[13]  + m[4]*m[1]*m[14] - m[4]*m[2]*m[13] - m[12]*m[1]*m[6]  + m[12]*m[2]*m[5];
    inv[3]  = -m[1]*m[6]*m[11]  + m[1]*m[7]*m[10]  + m[5]*m[2]*m[11] - m[5]*m[3]*m[10] - m[9]*m[2]*m[7]   + m[9]*m[3]*m[6];
    inv[7]  =  m[0]*m[6]*m[11]  - m[0]*m[7]*m[10]  - m[4]*m[2]*m[11] + m[4]*m[3]*m[10] + m[8]*m[2]*m[7]   - m[8]*m[3]*m[6];
    inv[11] = -m[0]*m[5]*m[11]  + m[0]*m[7]*m[9]   + m[4]*m[1]*m[11] - m[4]*m[3]*m[9]  - m[8]*m[1]*m[7]   + m[8]*m[3]*m[5];
    inv[15] =  m[0]*m[5]*m[10]  - m[0]*m[6]*m[9]   - m[4]*m[1]*m[10] + m[4]*m[2]*m[9]  + m[8]*m[1]*m[6]   - m[8]*m[2]*m[5];
    double det = m[0]*inv[0] + m[1]*inv[4] + m[2]*inv[8] + m[3]*inv[12];
    det = 1.0 / det;
#pragma unroll
    for (int i = 0; i < 16; ++i) invOut[i] = inv[i] * det;
}

__device__ __forceinline__ void matmul4(const double* A, const double* B, double* C)
{
#pragma unroll
    for (int r = 0; r < 4; ++r)
#pragma unroll
        for (int c = 0; c < 4; ++c) {
            double s = 0.0;
#pragma unroll
            for (int k = 0; k < 4; ++k) s += A[r * 4 + k] * B[k * 4 + c];
            C[r * 4 + c] = s;
        }
}

// ---------------- mm_features: (b,48,h,w) -> (b,17,h,w) --------------------
__global__ __launch_bounds__(256)
void mm_features_kernel(const float* __restrict__ y, float* __restrict__ m, int HW, int n)
{
    int p = blockIdx.x * 256 + threadIdx.x;
    if (p >= n) return;
    int b  = p / HW;
    int sp = p - b * HW;
    const float* base = y + (size_t)b * 48 * HW + sp;

    double A[16];
#pragma unroll
    for (int i = 0; i < 16; ++i) {
        double e = (i == 0 || i == 5 || i == 10 || i == 15) ? 1e-4 : 0.0;
        A[i] = (double)base[(16 + i) * HW] + e;
    }
    double iA[16];
    inv4x4(A, iA);                     // A dead

    double F[16];
    double s = 0.0;
#pragma unroll
    for (int i = 0; i < 16; ++i) { F[i] = (double)base[i * HW]; }
#pragma unroll
    for (int i = 0; i < 16; ++i) s += F[i];
    s *= (1.0 / 16.0);

    double T[16];
    matmul4(iA, F, T);                 // iA, F dead

    double Wm[16];
#pragma unroll
    for (int i = 0; i < 16; ++i) {
        double e = (i == 0 || i == 5 || i == 10 || i == 15) ? 1e-4 : 0.0;
        Wm[i] = (double)base[(32 + i) * HW] + e;
    }
    double iW[16];
    inv4x4(Wm, iW);                    // Wm dead

    double M[16];
    matmul4(T, iW, M);

    float* ob = m + (size_t)b * 17 * HW + sp;
    ob[0] = (float)s;
#pragma unroll
    for (int i = 0; i < 16; ++i) ob[(1 + i) * HW] = (float)M[i];
}

// ---------------- 4x4 maxpool: (2,48,512,512) -> (2,48,128,128) ------------
__global__ __launch_bounds__(256)
void maxpool4_kernel(const float* __restrict__ in, float* __restrict__ out, int n)
{
    int idx = blockIdx.x * 256 + threadIdx.x;
    if (idx >= n) return;
    int ow = idx & 127;
    int oh = (idx >> 7) & 127;
    int ct = idx >> 14;                 // b*48 + c
    const float* p = in + ct * 262144 + (oh * 4) * 512 + ow * 4;
    float mx = -3.4e38f;
#pragma unroll
    for (int r = 0; r < 4; ++r) {
        float4 v = *(const float4*)(p + r * 512);
        mx = fmaxf(mx, fmaxf(fmaxf(v.x, v.y), fmaxf(v.z, v.w)));
    }
    out[idx] = mx;
}

// ---------------- bicubic x4 upsample 128->512, align_corners, a=-0.75 -----
__device__ __forceinline__ double cubw(double t)
{
    const double a = -0.75;
    t = fabs(t);
    if (t <= 1.0) return ((a + 2.0) * t - (a + 3.0)) * t * t + 1.0;
    if (t < 2.0)  return (((t - 5.0) * t + 8.0) * t - 4.0) * a;
    return 0.0;
}

__global__ __launch_bounds__(256)
void bicubic_up4_kernel(const float* __restrict__ src, float* __restrict__ dst, int n)
{
    int idx = blockIdx.x * 256 + threadIdx.x;
    if (idx >= n) return;
    int P  = idx & 511;
    int O  = (idx >> 9) & 511;
    int bc = idx >> 18;                 // b*17 + c
    const double scale = 127.0 / 511.0;
    double sh = O * scale, sw = P * scale;
    int i0 = (int)floor(sh), j0 = (int)floor(sw);
    double wh[4], ww[4];
#pragma unroll
    for (int k = 0; k < 4; ++k) {
        wh[k] = cubw(sh - (double)(i0 + k - 1));
        ww[k] = cubw(sw - (double)(j0 + k - 1));
    }
    const float* sp = src + bc * 16384;
    double acc = 0.0;
#pragma unroll
    for (int ki = 0; ki < 4; ++ki) {
        int ih = min(max(i0 - 1 + ki, 0), 127);
        double rs = 0.0;
#pragma unroll
        for (int kj = 0; kj < 4; ++kj) {
            int iw = min(max(j0 - 1 + kj, 0), 127);
            rs += ww[kj] * (double)sp[ih * 128 + iw];
        }
        acc += wh[ki] * rs;
    }
    dst[idx] = (float)acc;
}

// ---------------------------------------------------------------------------
extern "C" void kernel_launch(void* const* d_in, const int* in_sizes, int n_in,
                              void* d_out, int out_size, void* d_ws, size_t ws_size,
                              hipStream_t stream)
{
    const float* x   = (const float*)d_in[0];
    const float* iW0 = (const float*)d_in[1];
    const float* iB0 = (const float*)d_in[2];
    const float* iW1 = (const float*)d_in[3];
    const float* iB1 = (const float*)d_in[4];
    const float* oW0 = (const float*)d_in[5];
    const float* oB0 = (const float*)d_in[6];
    const float* oW1 = (const float*)d_in[7];
    const float* oB1 = (const float*)d_in[8];
    float* out = (float*)d_out;
    float* ws  = (float*)d_ws;

    // workspace layout (floats)
    float* y0 = ws;                     //  2*48*512*512 = 25165824
    float* m0 = ws + 25165824;          //  2*17*512*512 =  8912896
    float* x1 = ws + 34078720;          //  2*48*128*128 =  1572864
    float* y1 = ws + 35651584;          //  1572864
    float* m1 = ws + 37224448;          //  2*17*128*128 =   557056
    float* u  = ws;                     //  reuse y0 region (y0 dead by then)

    // level 0
    conv3x3_leaky<48, 8, 8, 64><<<dim3(8, 16, 12), 256, 0, stream>>>(
        x, iW0, iB0, y0, 512, 512, 48, 6, 48 * 512 * 512, 48 * 512 * 512, 0);
    mm_features_kernel<<<(2 * 512 * 512) / 256, 256, 0, stream>>>(y0, m0, 512 * 512, 2 * 512 * 512);
    conv3x3_leaky<17, 9, 8, 64><<<dim3(8, 16, 4), 256, 0, stream>>>(
        m0, oW0, oB0, out, 512, 512, 17, 2, 17 * 512 * 512, 34 * 512 * 512, 0);
    maxpool4_kernel<<<(2 * 48 * 128 * 128) / 256, 256, 0, stream>>>(y0, x1, 2 * 48 * 128 * 128);

    // level 1 (128^2: 32x32 tiles, OCPT=4 -> 384 blocks)
    conv3x3_leaky<48, 4, 4, 32><<<dim3(4, 4, 24), 256, 0, stream>>>(
        x1, iW1, iB1, y1, 128, 128, 48, 12, 48 * 128 * 128, 48 * 128 * 128, 0);
    mm_features_kernel<<<(2 * 128 * 128) / 256, 256, 0, stream>>>(y1, m1, 128 * 128, 2 * 128 * 128);
    bicubic_up4_kernel<<<(2 * 17 * 512 * 512) / 256, 256, 0, stream>>>(m1, u, 2 * 17 * 512 * 512);
    conv3x3_leaky<17, 9, 8, 64><<<dim3(8, 16, 4), 256, 0, stream>>>(
        u, oW1, oB1, out, 512, 512, 17, 2, 17 * 512 * 512, 34 * 512 * 512, 17);
}